// Round 1
// baseline (179.199 us; speedup 1.0000x reference)
//
#include <hip/hip_runtime.h>
#include <hip/hip_bf16.h>
#include <stdint.h>

// Problem constants
#define N_TOK 8192      // 8 * 32 * 32 tokens, global attention
#define DDIM  128       // key/value size
#define CK    64        // keys per staged chunk
#define KSPLIT 4        // key-dimension split (512 blocks total)
#define KEYS_PER (N_TOK / KSPLIT)     // 2048
#define CHUNKS   (KEYS_PER / CK)      // 32

typedef short short8 __attribute__((ext_vector_type(8)));
typedef float f32x4  __attribute__((ext_vector_type(4)));
typedef short8 short8_ma __attribute__((may_alias));

__device__ __forceinline__ short f2bf(float f) {
  union { float f; uint32_t u; } a; a.f = f;
  uint32_t r = a.u + 0x7fffu + ((a.u >> 16) & 1u);   // RNE
  return (short)(r >> 16);
}
__device__ __forceinline__ float bf2f(short s) {
  union { float f; uint32_t u; } a; a.u = ((uint32_t)(uint16_t)s) << 16;
  return a.f;
}

// async global->LDS, 16B per lane. LDS dest is wave-uniform base + lane*16.
__device__ __forceinline__ void gload_lds16(const short* g, short* l) {
  __builtin_amdgcn_global_load_lds(
      (const __attribute__((address_space(1))) void*)g,
      (__attribute__((address_space(3))) void*)l, 16, 0, 0);
}

// ---------------- prep: Q,K transpose to [token][c] bf16 -------------------
// x: [8][384][1024] fp32. Qb/Kb: [8192][128] bf16 bits.
__global__ void prep_transpose(const float* __restrict__ x,
                               short* __restrict__ Qb, short* __restrict__ Kb) {
  __shared__ float t[32][33];
  const int b   = blockIdx.z >> 1;
  const int isQ = blockIdx.z & 1;
  const int c0  = (isQ ? 256 : 128) + blockIdx.y * 32;
  const int p0  = blockIdx.x * 32;
  const float* src = x + ((size_t)b * 384 + c0) * 1024 + p0;
  t[threadIdx.y][threadIdx.x] = src[threadIdx.y * 1024 + threadIdx.x]; // coalesced in p
  __syncthreads();
  short* dst = isQ ? Qb : Kb;
  const float v = t[threadIdx.x][threadIdx.y];
  dst[((size_t)b * 1024 + p0 + threadIdx.y) * DDIM + blockIdx.y * 32 + threadIdx.x] = f2bf(v);
}

// ---------------- prep: V straight copy to channel-major [128][8192] ------
__global__ void prep_v(const float* __restrict__ x, short* __restrict__ Vt) {
  const int o = blockIdx.x * 256 + threadIdx.x;     // < 128*8192
  const int v = o >> 13, n = o & 8191;
  const int b = n >> 10, p = n & 1023;
  Vt[o] = f2bf(x[((size_t)b * 384 + v) * 1024 + p]);
}

// ---------------- staging: crumb layouts (conflict-minimal frag reads) ----
// buf layout (shorts): K: [chi 16][key 64][clo 8]  (8192)
//                      V: [khi  8][v 128][klo 8]  (8192, at +8192)
__device__ __forceinline__ void stage_chunk(const short* __restrict__ Kb,
                                            const short* __restrict__ Vt,
                                            short* buf, int kb0, int wave, int lane) {
#pragma unroll
  for (int j = 0; j < 4; ++j) {
    const int chi = wave * 4 + j;
    gload_lds16(Kb + (size_t)(kb0 + lane) * DDIM + chi * 8, buf + chi * 512);
  }
#pragma unroll
  for (int j = 0; j < 4; ++j) {
    const int c2 = wave * 4 + j;
    const int khi = c2 >> 1, half = c2 & 1;
    gload_lds16(Vt + (size_t)(half * 64 + lane) * N_TOK + kb0 + khi * 8,
                buf + 8192 + khi * 1024 + half * 512);
  }
}

// ---------------- flash attention, split-K partials -----------------------
// grid (128 qtiles, 4 ksplits), 256 threads (4 waves x 16 Q rows).
// Opart: [qt*4+ks][64][128] bf16 (unnormalized); Ml: float2 {m(log2), l}.
__global__ __launch_bounds__(256, 2) void flash_attn(
    const short* __restrict__ Qb, const short* __restrict__ Kb,
    const short* __restrict__ Vt, short* __restrict__ Opart,
    float2* __restrict__ Ml) {
  __shared__ short lds[36864];  // 2x(K 16KB + V 16KB) + 4x P 2KB = 72 KB

  const int tid = threadIdx.x;
  const int wave = tid >> 6, lane = tid & 63;
  const int quad = lane >> 4, l16 = lane & 15;
  const int qt = blockIdx.x, ks = blockIdx.y;
  const int q0 = qt * 64;
  const int k0 = ks * KEYS_PER;

  short* Psh = lds + 32768 + wave * 1024;  // [khi 8][m 16][klo 8] per wave

  // Q fragments in registers: A[m=l16][k=quad*8+j], 4 k-blocks of 32
  short8 qf[4];
  {
    const short* qp = Qb + (size_t)(q0 + wave * 16 + l16) * DDIM + quad * 8;
#pragma unroll
    for (int kb = 0; kb < 4; ++kb) qf[kb] = *(const short8_ma*)(qp + kb * 32);
  }

  f32x4 O[8];
#pragma unroll
  for (int vb = 0; vb < 8; ++vb) O[vb] = (f32x4){0.f, 0.f, 0.f, 0.f};
  float mrow[4] = {-1e30f, -1e30f, -1e30f, -1e30f};
  float lrow[4] = {0.f, 0.f, 0.f, 0.f};

  const float SC = 0.08838834764831845f * 1.4426950408889634f;  // 1/sqrt(128)*log2(e)

  stage_chunk(Kb, Vt, lds, k0, wave, lane);  // chunk 0 -> buf 0

  for (int ch = 0; ch < CHUNKS; ++ch) {
    __syncthreads();  // drains vmcnt: buf[ch&1] staged; prev chunk compute done
    short* buf = lds + (ch & 1) * 16384;
    if (ch + 1 < CHUNKS)
      stage_chunk(Kb, Vt, lds + ((ch + 1) & 1) * 16384, k0 + (ch + 1) * CK, wave, lane);

    const short* KshB = buf;
    const short* VshB = buf + 8192;

    // S = Q K^T  (C-layout: row m = quad*4+r, col key = cb*16+l16)
    f32x4 S[4];
#pragma unroll
    for (int cb = 0; cb < 4; ++cb) S[cb] = (f32x4){0.f, 0.f, 0.f, 0.f};
#pragma unroll
    for (int kb = 0; kb < 4; ++kb) {
#pragma unroll
      for (int cb = 0; cb < 4; ++cb) {
        short8 bfr = *(const short8_ma*)(KshB + (((kb * 4 + quad) * 64) + cb * 16 + l16) * 8);
        S[cb] = __builtin_amdgcn_mfma_f32_16x16x32_bf16(qf[kb], bfr, S[cb], 0, 0, 0);
      }
    }

    // online softmax (exp2 domain)
    float rmax[4];
#pragma unroll
    for (int r = 0; r < 4; ++r)
      rmax[r] = fmaxf(fmaxf(S[0][r], S[1][r]), fmaxf(S[2][r], S[3][r]));
#pragma unroll
    for (int off = 1; off < 16; off <<= 1) {
#pragma unroll
      for (int r = 0; r < 4; ++r)
        rmax[r] = fmaxf(rmax[r], __shfl_xor(rmax[r], off, 64));
    }

    float alpha[4], rsum[4], pv[4][4];
#pragma unroll
    for (int r = 0; r < 4; ++r) {
      const float mnew = fmaxf(mrow[r], rmax[r] * SC);
      alpha[r] = exp2f(mrow[r] - mnew);
      mrow[r] = mnew;
      rsum[r] = 0.f;
#pragma unroll
      for (int cb = 0; cb < 4; ++cb) {
        const float p = exp2f(fmaf(S[cb][r], SC, -mnew));
        pv[cb][r] = p;
        rsum[r] += p;
      }
    }
#pragma unroll
    for (int off = 1; off < 16; off <<= 1) {
#pragma unroll
      for (int r = 0; r < 4; ++r) rsum[r] += __shfl_xor(rsum[r], off, 64);
    }
#pragma unroll
    for (int r = 0; r < 4; ++r) lrow[r] = lrow[r] * alpha[r] + rsum[r];

    // P: C-layout -> A-layout crumbs in per-wave LDS
#pragma unroll
    for (int cb = 0; cb < 4; ++cb) {
#pragma unroll
      for (int r = 0; r < 4; ++r)
        Psh[((cb * 2 + (l16 >> 3)) * 16 + quad * 4 + r) * 8 + (l16 & 7)] = f2bf(pv[cb][r]);
    }

    // rescale O by alpha (per-row)
#pragma unroll
    for (int vb = 0; vb < 8; ++vb) {
#pragma unroll
      for (int r = 0; r < 4; ++r) O[vb][r] *= alpha[r];
    }

    // within-wave LDS ordering: wait DS ops only (keep vmcnt prefetch in flight)
    __builtin_amdgcn_sched_barrier(0);
    __builtin_amdgcn_s_waitcnt(0xC07F);  // lgkmcnt(0)
    __builtin_amdgcn_sched_barrier(0);

    // O += P V
#pragma unroll
    for (int kstep = 0; kstep < 2; ++kstep) {
      short8 pa = *(const short8_ma*)(Psh + ((kstep * 4 + quad) * 16 + l16) * 8);
#pragma unroll
      for (int vb = 0; vb < 8; ++vb) {
        short8 bv = *(const short8_ma*)(VshB + ((kstep * 4 + quad) * 128 + vb * 16 + l16) * 8);
        O[vb] = __builtin_amdgcn_mfma_f32_16x16x32_bf16(pa, bv, O[vb], 0, 0, 0);
      }
    }
  }

  // epilogue: unnormalized partials
  const int blk = qt * KSPLIT + ks;
  short* Op = Opart + (size_t)blk * (64 * DDIM);
#pragma unroll
  for (int vb = 0; vb < 8; ++vb) {
#pragma unroll
    for (int r = 0; r < 4; ++r)
      Op[(wave * 16 + quad * 4 + r) * DDIM + vb * 16 + l16] = f2bf(O[vb][r]);
  }
  if (l16 < 4) {
    float mv = mrow[0], lv = lrow[0];
    if (l16 == 1) { mv = mrow[1]; lv = lrow[1]; }
    else if (l16 == 2) { mv = mrow[2]; lv = lrow[2]; }
    else if (l16 == 3) { mv = mrow[3]; lv = lrow[3]; }
    Ml[blk * 64 + wave * 16 + quad * 4 + l16] = make_float2(mv, lv);
  }
}

// ---------------- combine splits + write [B,V,H,W] ------------------------
__global__ void combine_kernel(const short* __restrict__ Opart,
                               const float2* __restrict__ Ml,
                               float* __restrict__ out) {
  const int o = blockIdx.x * 256 + threadIdx.x;  // < 1048576
  const int b = o >> 17, rem = o & 131071;
  const int v = rem >> 10, p = rem & 1023;
  const int n = (b << 10) + p;
  const int qt = n >> 6, row = n & 63;

  float mk[KSPLIT], lk[KSPLIT];
  float M = -1e30f;
#pragma unroll
  for (int s = 0; s < KSPLIT; ++s) {
    const float2 ml = Ml[(qt * KSPLIT + s) * 64 + row];
    mk[s] = ml.x; lk[s] = ml.y;
    M = fmaxf(M, mk[s]);
  }
  float num = 0.f, den = 0.f;
#pragma unroll
  for (int s = 0; s < KSPLIT; ++s) {
    const float w = exp2f(mk[s] - M);
    num += w * bf2f(Opart[(size_t)(qt * KSPLIT + s) * (64 * DDIM) + row * DDIM + v]);
    den += w * lk[s];
  }
  out[o] = num / den;
}

// ---------------- launch ---------------------------------------------------
extern "C" void kernel_launch(void* const* d_in, const int* in_sizes, int n_in,
                              void* d_out, int out_size, void* d_ws, size_t ws_size,
                              hipStream_t stream) {
  const float* x = (const float*)d_in[0];
  float* out = (float*)d_out;
  char* ws = (char*)d_ws;
  // ws layout (needs ~14.3 MB):
  short* Qb    = (short*)(ws);                     // 2 MB
  short* Kb    = (short*)(ws + (2u << 20));        // 2 MB
  short* Vt    = (short*)(ws + (4u << 20));        // 2 MB
  short* Opart = (short*)(ws + (6u << 20));        // 8 MB
  float2* Ml   = (float2*)(ws + (14u << 20));      // 256 KB

  prep_transpose<<<dim3(32, 4, 16), dim3(32, 32), 0, stream>>>(x, Qb, Kb);
  prep_v<<<dim3(512 * DDIM * N_TOK / (512 * 256)), dim3(256), 0, stream>>>(x, Vt);
  flash_attn<<<dim3(128, KSPLIT), dim3(256), 0, stream>>>(Qb, Kb, Vt, Opart, Ml);
  combine_kernel<<<dim3(4096), dim3(256), 0, stream>>>(Opart, Ml, out);
}

// Round 4
// 118.326 us; speedup vs baseline: 1.5144x; 1.5144x over previous
//
#include <hip/hip_runtime.h>
#include <hip/hip_bf16.h>
#include <stdint.h>

#define N_TOK 8192
#define DDIM  128

typedef _Float16 half2v __attribute__((ext_vector_type(2)));
typedef _Float16 half4v __attribute__((ext_vector_type(4)));
typedef _Float16 half8v __attribute__((ext_vector_type(8)));
typedef float f32x4 __attribute__((ext_vector_type(4)));
typedef half4v half4_ma __attribute__((may_alias));
typedef half8v half8_ma __attribute__((may_alias));
typedef float4 float4_ma __attribute__((may_alias));

#define MFMA16 __builtin_amdgcn_mfma_f32_16x16x16f16   // legacy spelling: no '_' before f16
#define MFMA32 __builtin_amdgcn_mfma_f32_16x16x32_f16

// 1/sqrt(128) * log2(e): folded into Q so inner loop is a bare v_exp_f32
#define QSCALE (0.08838834764831845f * 1.4426950408889634f)

__device__ __forceinline__ half2v pkrtz(float a, float b) {
  return __builtin_bit_cast(half2v, __builtin_amdgcn_cvt_pkrtz(a, b));
}

__device__ __forceinline__ void gload_lds16(const _Float16* g, _Float16* l) {
  __builtin_amdgcn_global_load_lds(
      (const __attribute__((address_space(1))) void*)g,
      (__attribute__((address_space(3))) void*)l, 16, 0, 0);
}

// ---------------- prep: Q (scaled), K transpose to [token][c] f16 ----------
__global__ void prep_qk(const float* __restrict__ x,
                        _Float16* __restrict__ Qf, _Float16* __restrict__ Kf) {
  __shared__ float t[32][33];
  const int b   = blockIdx.z >> 1;
  const int isQ = blockIdx.z & 1;
  const int c0  = (isQ ? 256 : 128) + blockIdx.y * 32;
  const int p0  = blockIdx.x * 32;
  const float* src = x + ((size_t)b * 384 + c0) * 1024 + p0;
  t[threadIdx.y][threadIdx.x] = src[threadIdx.y * 1024 + threadIdx.x];
  __syncthreads();
  float v = t[threadIdx.x][threadIdx.y];
  if (isQ) v *= QSCALE;
  _Float16* dst = isQ ? Qf : Kf;
  dst[((size_t)b * 1024 + p0 + threadIdx.y) * DDIM + blockIdx.y * 32 + threadIdx.x] = (_Float16)v;
}

// ---------------- prep: V straight copy to channel-major [128][8192] ------
__global__ void prep_v(const float* __restrict__ x, _Float16* __restrict__ Vt) {
  const int i4 = (blockIdx.x * 256 + threadIdx.x) * 4;   // < 128*8192
  const int v = i4 >> 13, n = i4 & 8191;
  const int b = n >> 10, p = n & 1023;
  const float4 s = *(const float4_ma*)(x + ((size_t)b * 384 + v) * 1024 + p);
  half4v h; h.x = (_Float16)s.x; h.y = (_Float16)s.y; h.z = (_Float16)s.z; h.w = (_Float16)s.w;
  *(half4_ma*)(Vt + (size_t)v * N_TOK + b * 1024 + p) = h;
}

// ---------------- flash attention, fixed-scale softmax, split-K ------------
// grid (64 qtiles of 128 rows, KS splits), 256 thr = 4 waves x 32 qrows.
// LDS buffer: K crumb [chi 16][key 64][clo 8]; V [v 128][g-swizzled 64].
// Opart: [s][v 128][q 8192] f16, pre-normalized. Lsum: [s][q] f32.
__global__ __launch_bounds__(256, 2) void flash_attn(
    const _Float16* __restrict__ Qf, const _Float16* __restrict__ Kf,
    const _Float16* __restrict__ Vt, _Float16* __restrict__ Opart,
    float* __restrict__ Lsum) {
  __shared__ _Float16 lds[32768];  // 2 x (K 16KB + V 16KB) = 64 KB

  const int tid = threadIdx.x;
  const int w = tid >> 6, lane = tid & 63;
  const int quad = lane >> 4, l16 = lane & 15;
  const int ks = blockIdx.y, KS = gridDim.y;
  const int kp = N_TOK / KS;          // keys per split
  const int chunks = kp >> 6;
  const int k0 = ks * kp;
  const int q0 = blockIdx.x * 128;

  // Q fragments (B-operand): lane holds Q[q=l16][c=quad*8+j], 2 q-tiles
  half8v qf[2][4];
#pragma unroll
  for (int qt = 0; qt < 2; ++qt) {
    const _Float16* qp = Qf + (size_t)(q0 + w * 32 + qt * 16 + l16) * DDIM + quad * 8;
#pragma unroll
    for (int kb = 0; kb < 4; ++kb) qf[qt][kb] = *(const half8_ma*)(qp + kb * 32);
  }

  f32x4 O[2][8];
#pragma unroll
  for (int qt = 0; qt < 2; ++qt)
#pragma unroll
    for (int vb = 0; vb < 8; ++vb) O[qt][vb] = (f32x4){0.f, 0.f, 0.f, 0.f};
  float ls[2] = {0.f, 0.f};

  // staging source pointers (advance per chunk)
  const _Float16* srcK[4];
  const _Float16* srcV[4];
  int vslot[4];
#pragma unroll
  for (int j = 0; j < 4; ++j) {
    srcK[j] = Kf + (size_t)(k0 + lane) * DDIM + (w * 4 + j) * 8;
    const int t = (w * 4 + j) * 64 + lane;
    const int v = t >> 3, h = t & 7;
    const int hs = h ^ ((v >> 1) & 7);          // xor-swizzle (granule, bit0-free)
    srcV[j] = Vt + (size_t)v * N_TOK + k0 + hs * 8;
    vslot[j] = (w * 4 + j) * 512;
  }

  // stage chunk 0 into buf 0
#pragma unroll
  for (int j = 0; j < 4; ++j) {
    gload_lds16(srcK[j], lds + vslot[j]);
    gload_lds16(srcV[j], lds + 8192 + vslot[j]);
  }

  for (int ch = 0; ch < chunks; ++ch) {
    __syncthreads();                       // buf[ch&1] ready
    _Float16* buf = lds + (ch & 1) * 16384;
    if (ch + 1 < chunks) {
      _Float16* nbuf = lds + ((ch + 1) & 1) * 16384;
      const int adv = (ch + 1) * 64;
#pragma unroll
      for (int j = 0; j < 4; ++j) {
        gload_lds16(srcK[j] + (size_t)adv * DDIM, nbuf + vslot[j]);
        gload_lds16(srcV[j] + adv, nbuf + 8192 + vslot[j]);
      }
    }
    const _Float16* Ksh = buf;
    const _Float16* Vsh = buf + 8192;

    // S^T = K Q^T : C-layout row=key (quad*4+r), col=q (l16)
    f32x4 S[2][4];
#pragma unroll
    for (int qt = 0; qt < 2; ++qt)
#pragma unroll
      for (int cb = 0; cb < 4; ++cb) S[qt][cb] = (f32x4){0.f, 0.f, 0.f, 0.f};
#pragma unroll
    for (int kb = 0; kb < 4; ++kb) {
#pragma unroll
      for (int cb = 0; cb < 4; ++cb) {
        half8v kf = *(const half8_ma*)(Ksh + (((kb * 4 + quad) * 64) + cb * 16 + l16) * 8);
        S[0][cb] = MFMA32(kf, qf[0][kb], S[0][cb], 0, 0, 0);
        S[1][cb] = MFMA32(kf, qf[1][kb], S[1][cb], 0, 0, 0);
      }
    }

    // P = exp2(S) (scale pre-folded into Q); pack into x16 B-operand layout
    half4v P[2][4];
#pragma unroll
    for (int qt = 0; qt < 2; ++qt) {
#pragma unroll
      for (int cb = 0; cb < 4; ++cb) {
        const float p0 = __builtin_amdgcn_exp2f(S[qt][cb][0]);
        const float p1 = __builtin_amdgcn_exp2f(S[qt][cb][1]);
        const float p2 = __builtin_amdgcn_exp2f(S[qt][cb][2]);
        const float p3 = __builtin_amdgcn_exp2f(S[qt][cb][3]);
        ls[qt] += (p0 + p1) + (p2 + p3);
        half2v lo = pkrtz(p0, p1);
        half2v hi = pkrtz(p2, p3);
        P[qt][cb] = __builtin_shufflevector(lo, hi, 0, 1, 2, 3);
      }
    }

    // O^T += V^T P^T : A = V-frag (b64, swizzled), B = P (registers)
#pragma unroll
    for (int cb = 0; cb < 4; ++cb) {
#pragma unroll
      for (int vb = 0; vb < 8; ++vb) {
        const int v = vb * 16 + l16;
        half4v vf = *(const half4_ma*)(Vsh + v * 64 + (((cb * 4 + quad) ^ (l16 & 14)) * 4));
        O[0][vb] = MFMA16(vf, P[0][cb], O[0][vb], 0, 0, 0);
        O[1][vb] = MFMA16(vf, P[1][cb], O[1][vb], 0, 0, 0);
      }
    }
  }

  // epilogue: reduce row sums across quads (keys), normalize, store
#pragma unroll
  for (int qt = 0; qt < 2; ++qt) {
    ls[qt] += __shfl_xor(ls[qt], 16, 64);
    ls[qt] += __shfl_xor(ls[qt], 32, 64);
  }
  const float rl[2] = {1.f / ls[0], 1.f / ls[1]};
#pragma unroll
  for (int qt = 0; qt < 2; ++qt) {
    const int q = q0 + w * 32 + qt * 16 + l16;
#pragma unroll
    for (int vb = 0; vb < 8; ++vb) {
#pragma unroll
      for (int r = 0; r < 4; ++r) {
        const int v = vb * 16 + quad * 4 + r;
        Opart[((size_t)ks * DDIM + v) * N_TOK + q] = (_Float16)(O[qt][vb][r] * rl[qt]);
      }
    }
  }
  if (lane < 16) {
#pragma unroll
    for (int qt = 0; qt < 2; ++qt)
      Lsum[(size_t)ks * N_TOK + q0 + w * 32 + qt * 16 + lane] = ls[qt];
  }
}

// ---------------- combine: l-weighted average of pre-normalized splits ----
__global__ void combine_kernel(const _Float16* __restrict__ Opart,
                               const float* __restrict__ Lsum,
                               float* __restrict__ out, int KS) {
  const int o = blockIdx.x * 256 + threadIdx.x;  // < 1048576
  const int b = o >> 17, v = (o >> 10) & 127, p = o & 1023;
  const int q = (b << 10) | p;
  float num = 0.f, den = 0.f;
  for (int s = 0; s < KS; ++s) {
    const float l = Lsum[(size_t)s * N_TOK + q];
    num += l * (float)Opart[((size_t)s * DDIM + v) * N_TOK + q];
    den += l;
  }
  out[o] = num / den;
}

// ---------------- launch ---------------------------------------------------
extern "C" void kernel_launch(void* const* d_in, const int* in_sizes, int n_in,
                              void* d_out, int out_size, void* d_ws, size_t ws_size,
                              hipStream_t stream) {
  const float* x = (const float*)d_in[0];
  float* out = (float*)d_out;
  char* ws = (char*)d_ws;

  // ws: Qf 2MB | Kf 2MB | Vt 2MB | Opart KS*2MB | Lsum KS*32KB
  const size_t need8 = (6u << 20) + 8 * (2u << 20) + (size_t)8 * N_TOK * 4;
  const int KS = (ws_size >= need8) ? 8 : 4;   // fall back to R1-proven 14.25MB

  _Float16* Qf    = (_Float16*)(ws);
  _Float16* Kf    = (_Float16*)(ws + (2u << 20));
  _Float16* Vt    = (_Float16*)(ws + (4u << 20));
  _Float16* Opart = (_Float16*)(ws + (6u << 20));
  float*    Lsum  = (float*)(ws + (6u << 20) + (size_t)KS * (2u << 20));

  prep_qk<<<dim3(32, 4, 16), dim3(32, 32), 0, stream>>>(x, Qf, Kf);
  prep_v<<<dim3(1024), dim3(256), 0, stream>>>(x, Vt);
  flash_attn<<<dim3(64, KS), dim3(256), 0, stream>>>(Qf, Kf, Vt, Opart, Lsum);
  combine_kernel<<<dim3(4096), dim3(256), 0, stream>>>(Opart, Lsum, out, KS);
}